// Round 1
// baseline (99.006 us; speedup 1.0000x reference)
//
#include <hip/hip_runtime.h>

// Problem constants (from reference):
//   lhs: [8, 1023, 768] f32, rhs: [8, 8192, 768] f32
//   N = 1024, F = 8192/1024 = 8, EXP = 1
//   out[b,n,m] = cos_sim(lhs[b,n], rhs[b,m]) if (m % 1024) == n+1 else -1e9
constexpr int B    = 8;
constexpr int N1   = 1023;
constexpr int NBLK = 1024;   // N
constexpr int D    = 768;
constexpr int F    = 8;
constexpr int NTOT = 8192;
constexpr float NEG = -1e9f;

__global__ __launch_bounds__(256)
void lcs_kernel(const float* __restrict__ lhs,
                const float* __restrict__ rhs,
                float* __restrict__ out) {
    // one block per (b, n, f): fills out[b, n, f*1024 .. f*1024+1023]
    int flat = blockIdx.x;
    int f = flat % F;
    int n = (flat / F) % N1;
    int b = flat / (F * N1);

    int t = threadIdx.x;

    const float4* l4 = (const float4*)(lhs + ((size_t)b * N1 + n) * D);
    const float4* r4 = (const float4*)(rhs + ((size_t)b * NTOT + (size_t)f * NBLK + (n + 1)) * D);

    // 768 floats = 192 float4; lanes 192..255 contribute zero partials
    float dot = 0.f, l2 = 0.f, r2 = 0.f;
    if (t < D / 4) {
        float4 a = l4[t];
        float4 c = r4[t];
        dot = a.x * c.x + a.y * c.y + a.z * c.z + a.w * c.w;
        l2  = a.x * a.x + a.y * a.y + a.z * a.z + a.w * a.w;
        r2  = c.x * c.x + c.y * c.y + c.z * c.z + c.w * c.w;
    }

    // wave (64-lane) butterfly reduce, then LDS across the 4 waves
    #pragma unroll
    for (int off = 32; off >= 1; off >>= 1) {
        dot += __shfl_xor(dot, off, 64);
        l2  += __shfl_xor(l2,  off, 64);
        r2  += __shfl_xor(r2,  off, 64);
    }
    __shared__ float sdot[4], sl2[4], sr2[4];
    int wave = t >> 6;
    if ((t & 63) == 0) { sdot[wave] = dot; sl2[wave] = l2; sr2[wave] = r2; }
    __syncthreads();
    float dsum = sdot[0] + sdot[1] + sdot[2] + sdot[3];
    float lsum = sl2[0]  + sl2[1]  + sl2[2]  + sl2[3];
    float rsum = sr2[0]  + sr2[1]  + sr2[2]  + sr2[3];
    float sim = dsum * rsqrtf(lsum * rsum);   // EXP == 1

    // write the 1024-float segment: 256 lanes x float4, aligned
    float4* o4 = (float4*)(out + ((size_t)b * N1 + n) * NTOT + (size_t)f * NBLK);
    int keep_col = n + 1;
    int c0 = t * 4;
    float4 v;
    v.x = (c0 + 0 == keep_col) ? sim : NEG;
    v.y = (c0 + 1 == keep_col) ? sim : NEG;
    v.z = (c0 + 2 == keep_col) ? sim : NEG;
    v.w = (c0 + 3 == keep_col) ? sim : NEG;
    o4[t] = v;
}

extern "C" void kernel_launch(void* const* d_in, const int* in_sizes, int n_in,
                              void* d_out, int out_size, void* d_ws, size_t ws_size,
                              hipStream_t stream) {
    const float* lhs = (const float*)d_in[0];
    const float* rhs = (const float*)d_in[1];
    float* out = (float*)d_out;

    int grid = B * N1 * F;  // 65472 blocks
    lcs_kernel<<<grid, 256, 0, stream>>>(lhs, rhs, out);
}

// Round 3
// 88.473 us; speedup vs baseline: 1.1191x; 1.1191x over previous
//
#include <hip/hip_runtime.h>

// lhs: [8, 1023, 768] f32, rhs: [8, 8192, 768] f32
// N = 1024, F = 8, EXP = 1
// out[b,n,m] = cos_sim(lhs[b,n], rhs[b,m]) if (m % 1024) == n+1 else -1e9
constexpr int B    = 8;
constexpr int N1   = 1023;
constexpr int NBLK = 1024;
constexpr int D    = 768;
constexpr int F    = 8;
constexpr int NTOT = 8192;
constexpr float NEG = -1e9f;

typedef float v4f __attribute__((ext_vector_type(4)));   // native clang vector: nt builtins accept it

__global__ __launch_bounds__(256)
void lcs_kernel(const float* __restrict__ lhs,
                const float* __restrict__ rhs,
                float* __restrict__ out) {
    // one WAVE per (b, n, f); 4 independent waves per block, no LDS, no barrier
    int t    = threadIdx.x;
    int wave = t >> 6;
    int lane = t & 63;
    int gi   = blockIdx.x * 4 + wave;        // [0, 65472)

    // n fastest-varying -> consecutive waves read consecutive rhs rows
    int n   = gi % N1;
    int tmp = gi / N1;
    int f   = tmp % F;
    int b   = tmp / F;

    const v4f* l4 = (const v4f*)(lhs + ((size_t)b * N1 + n) * D);
    const v4f* r4 = (const v4f*)(rhs + ((size_t)b * NTOT + (size_t)f * NBLK + (n + 1)) * D);
    v4f*       o4 = (v4f*)(out + ((size_t)b * N1 + n) * NTOT + (size_t)f * NBLK);

    int keep_col   = n + 1;                  // column within the 1024-segment
    int keep_q     = keep_col >> 2;          // which float4 [0,256)
    int owner_lane = keep_q & 63;
    int owner_it   = keep_q >> 6;

    // 1) fire-and-forget NEG stores (255/256 float4s) — independent of loads
    v4f neg4 = {NEG, NEG, NEG, NEG};
    #pragma unroll
    for (int it = 0; it < 4; ++it) {
        if (!(lane == owner_lane && it == owner_it)) {
            __builtin_nontemporal_store(neg4, &o4[it * 64 + lane]);
        }
    }

    // 2) loads: 192 float4 per row, 3 per lane. rhs is read-once -> nt loads.
    v4f a0 = l4[lane];
    v4f a1 = l4[lane + 64];
    v4f a2 = l4[lane + 128];
    v4f c0 = __builtin_nontemporal_load(&r4[lane]);
    v4f c1 = __builtin_nontemporal_load(&r4[lane + 64]);
    v4f c2 = __builtin_nontemporal_load(&r4[lane + 128]);

    float dot = a0.x*c0.x + a0.y*c0.y + a0.z*c0.z + a0.w*c0.w
              + a1.x*c1.x + a1.y*c1.y + a1.z*c1.z + a1.w*c1.w
              + a2.x*c2.x + a2.y*c2.y + a2.z*c2.z + a2.w*c2.w;
    float l2  = a0.x*a0.x + a0.y*a0.y + a0.z*a0.z + a0.w*a0.w
              + a1.x*a1.x + a1.y*a1.y + a1.z*a1.z + a1.w*a1.w
              + a2.x*a2.x + a2.y*a2.y + a2.z*a2.z + a2.w*a2.w;
    float r2  = c0.x*c0.x + c0.y*c0.y + c0.z*c0.z + c0.w*c0.w
              + c1.x*c1.x + c1.y*c1.y + c1.z*c1.z + c1.w*c1.w
              + c2.x*c2.x + c2.y*c2.y + c2.z*c2.z + c2.w*c2.w;

    // 3) 64-lane butterfly reduce (all lanes end with the full sums)
    #pragma unroll
    for (int off = 32; off >= 1; off >>= 1) {
        dot += __shfl_xor(dot, off, 64);
        l2  += __shfl_xor(l2,  off, 64);
        r2  += __shfl_xor(r2,  off, 64);
    }
    float sim = dot * rsqrtf(l2 * r2);       // EXP == 1

    // 4) owner writes the one float4 containing the kept column
    if (lane == owner_lane) {
        int r = keep_col & 3;
        v4f v;
        v.x = (r == 0) ? sim : NEG;
        v.y = (r == 1) ? sim : NEG;
        v.z = (r == 2) ? sim : NEG;
        v.w = (r == 3) ? sim : NEG;
        __builtin_nontemporal_store(v, &o4[owner_it * 64 + owner_lane]);
    }
}

extern "C" void kernel_launch(void* const* d_in, const int* in_sizes, int n_in,
                              void* d_out, int out_size, void* d_ws, size_t ws_size,
                              hipStream_t stream) {
    const float* lhs = (const float*)d_in[0];
    const float* rhs = (const float*)d_in[1];
    float* out = (float*)d_out;

    int grid = (B * N1 * F) / 4;  // 16368 blocks, 4 waves each
    lcs_kernel<<<grid, 256, 0, stream>>>(lhs, rhs, out);
}